// Round 3
// baseline (1661.762 us; speedup 1.0000x reference)
//
#include <hip/hip_runtime.h>
#include <hip/hip_bf16.h>

#define NNODES 12000
#define NEDGES 384000
#define NETOT  (NEDGES + NNODES)   /* 396000 incl self-loops */
#define FIN    4
#define FHID   50
#define FOUT   1433
#define KP     1440                /* FOUT padded to multiple of 32 */
#define MP     12032               /* NNODES padded to multiple of 128 */
#define NEG_SLOPE 0.2f

typedef __hip_bfloat16 bf16_t;
typedef __bf16 bf16x8 __attribute__((ext_vector_type(8)));
typedef float  f32x4  __attribute__((ext_vector_type(4)));

__device__ __forceinline__ float  b2f(bf16_t h) { return __bfloat162float(h); }
__device__ __forceinline__ bf16_t f2b(float f)  { return __float2bfloat16(f); }

// ---------------- init: deg=1 (self loop), zero pad rows of h2 ----------------
__global__ void k_init(int* __restrict__ deg, bf16_t* __restrict__ h2) {
    int i = blockIdx.x * blockDim.x + threadIdx.x;
    int stride = gridDim.x * blockDim.x;
    for (int v = i; v < NNODES; v += stride) deg[v] = 1;
    const size_t padN = (size_t)(MP - NNODES) * KP;
    for (size_t t = i; t < padN; t += stride) h2[(size_t)NNODES * KP + t] = f2b(0.f);
}

// ---------------- count real edges by dst ----------------
__global__ void k_count(const int* __restrict__ ei, int* __restrict__ deg) {
    int i = blockIdx.x * blockDim.x + threadIdx.x;
    if (i < NEDGES) atomicAdd(&deg[ei[NEDGES + i]], 1);
}

// ---------------- single-block exclusive scan -> rowptr[N+1] ----------------
__global__ __launch_bounds__(1024) void k_scan(const int* __restrict__ deg, int* __restrict__ rowptr) {
    __shared__ int sd[1024];
    __shared__ int carry;
    int tid = threadIdx.x;
    if (tid == 0) { carry = 0; rowptr[0] = 0; }
    __syncthreads();
    for (int base = 0; base < NNODES; base += 1024) {
        int v = (base + tid < NNODES) ? deg[base + tid] : 0;
        sd[tid] = v;
        __syncthreads();
        for (int off = 1; off < 1024; off <<= 1) {
            int t = (tid >= off) ? sd[tid - off] : 0;
            __syncthreads();
            sd[tid] += t;
            __syncthreads();
        }
        int inc = sd[tid] + carry;
        if (base + tid < NNODES) rowptr[base + tid + 1] = inc;
        __syncthreads();
        if (tid == 1023) carry = sd[1023] + carry;
        __syncthreads();
    }
}

__global__ void k_cursor(const int* __restrict__ rowptr, int* __restrict__ cursor) {
    int i = blockIdx.x * blockDim.x + threadIdx.x;
    if (i < NNODES) cursor[i] = rowptr[i];
}

// ---------------- fill CSR src lists (incl self loops) ----------------
__global__ void k_fill(const int* __restrict__ ei, int* __restrict__ cursor, int* __restrict__ csrc) {
    int i = blockIdx.x * blockDim.x + threadIdx.x;
    if (i < NETOT) {
        int s, d;
        if (i < NEDGES) { s = ei[i]; d = ei[NEDGES + i]; }
        else            { s = d = i - NEDGES; }
        int pos = atomicAdd(&cursor[d], 1);
        csrc[pos] = s;
    }
}

// ---------------- layer1 linear: h1pre = x @ W1, al1/ar1 logit parts ----------------
__global__ __launch_bounds__(256) void k_linear1(
        const bf16_t* __restrict__ x, const bf16_t* __restrict__ W1,
        const bf16_t* __restrict__ as1, const bf16_t* __restrict__ ad1,
        float* __restrict__ h1pre, float* __restrict__ al, float* __restrict__ ar) {
    __shared__ float sW[FIN * FHID];
    __shared__ float sa[FHID], sdl[FHID];
    int tid = threadIdx.x;
    if (tid < FIN * FHID) sW[tid] = b2f(W1[tid]);
    if (tid < FHID) { sa[tid] = b2f(as1[tid]); sdl[tid] = b2f(ad1[tid]); }
    __syncthreads();
    int i = blockIdx.x * 256 + tid;
    if (i >= NNODES) return;
    float x0 = b2f(x[i * 4 + 0]), x1 = b2f(x[i * 4 + 1]);
    float x2 = b2f(x[i * 4 + 2]), x3 = b2f(x[i * 4 + 3]);
    float hal = 0.f, har = 0.f;
    for (int j = 0; j < FHID; ++j) {
        float h = x0 * sW[j] + x1 * sW[FHID + j] + x2 * sW[2 * FHID + j] + x3 * sW[3 * FHID + j];
        h1pre[(size_t)i * FHID + j] = h;
        hal += h * sa[j];
        har += h * sdl[j];
    }
    al[i] = hal; ar[i] = har;
}

// ---------------- layer1 softmax-aggregate (one wave per dst) ----------------
__global__ __launch_bounds__(64) void k_agg1(
        const float* __restrict__ h1pre, const float* __restrict__ al, const float* __restrict__ ar,
        const int* __restrict__ rowptr, const int* __restrict__ csrc,
        const bf16_t* __restrict__ b1, float* __restrict__ h1) {
    int v = blockIdx.x, tid = threadIdx.x;
    int s0 = rowptr[v], s1 = rowptr[v + 1];
    float arv = ar[v];
    float m = -1e30f;
    for (int e = s0 + tid; e < s1; e += 64) {
        float l = al[csrc[e]] + arv;
        l = l > 0.f ? l : NEG_SLOPE * l;
        m = fmaxf(m, l);
    }
#pragma unroll
    for (int off = 32; off; off >>= 1) m = fmaxf(m, __shfl_xor(m, off, 64));
    __shared__ float sw[64];
    __shared__ int ssrc[64];
    float acc = 0.f, ssum = 0.f;
    for (int base = s0; base < s1; base += 64) {
        int e = base + tid;
        float w = 0.f; int si = 0;
        if (e < s1) {
            si = csrc[e];
            float l = al[si] + arv;
            l = l > 0.f ? l : NEG_SLOPE * l;
            w = __expf(l - m);
        }
        ssum += w;
        sw[tid] = w; ssrc[tid] = si;
        __syncthreads();
        int cnt = min(64, s1 - base);
        if (tid < FHID) {
            for (int j = 0; j < cnt; ++j)
                acc += sw[j] * h1pre[(size_t)ssrc[j] * FHID + tid];
        }
        __syncthreads();
    }
#pragma unroll
    for (int off = 32; off; off >>= 1) ssum += __shfl_xor(ssum, off, 64);
    if (tid < FHID) {
        float o = acc / ssum + b2f(b1[tid]);
        h1[(size_t)v * FHID + tid] = fmaxf(o, 0.f);
    }
}

// ---------------- layer2 linear: h2pre = h1 @ W2 (bf16, stride KP), al2/ar2 ----------------
__global__ __launch_bounds__(256) void k_linear2(
        const float* __restrict__ h1, const bf16_t* __restrict__ W2,
        const bf16_t* __restrict__ as2, const bf16_t* __restrict__ ad2,
        bf16_t* __restrict__ h2pre, float* __restrict__ al2, float* __restrict__ ar2) {
    int v = blockIdx.x, tid = threadIdx.x;
    __shared__ float sh[FHID];
    if (tid < FHID) sh[tid] = h1[(size_t)v * FHID + tid];
    __syncthreads();
    float pal = 0.f, par = 0.f;
    for (int f = tid; f < KP; f += 256) {
        float a = 0.f;
        if (f < FOUT) {
#pragma unroll 10
            for (int k = 0; k < FHID; ++k) a += sh[k] * b2f(W2[k * FOUT + f]);
            pal += a * b2f(as2[f]);
            par += a * b2f(ad2[f]);
        }
        h2pre[(size_t)v * KP + f] = f2b(a);
    }
#pragma unroll
    for (int off = 32; off; off >>= 1) { pal += __shfl_xor(pal, off, 64); par += __shfl_xor(par, off, 64); }
    __shared__ float rA[4], rB[4];
    int wave = tid >> 6, lane = tid & 63;
    if (lane == 0) { rA[wave] = pal; rB[wave] = par; }
    __syncthreads();
    if (tid == 0) {
        al2[v] = rA[0] + rA[1] + rA[2] + rA[3];
        ar2[v] = rB[0] + rB[1] + rB[2] + rB[3];
    }
}

// ---------------- layer2 softmax-aggregate (block of 256 per dst), writes h2 bf16 [MP][KP] ----------------
__global__ __launch_bounds__(256) void k_agg2(
        const bf16_t* __restrict__ h2pre, const float* __restrict__ al, const float* __restrict__ ar,
        const int* __restrict__ rowptr, const int* __restrict__ csrc,
        const bf16_t* __restrict__ b2, bf16_t* __restrict__ h2) {
    int v = blockIdx.x, tid = threadIdx.x;
    int s0 = rowptr[v], s1 = rowptr[v + 1];
    float arv = ar[v];
    float m = -1e30f;
    for (int e = s0 + tid; e < s1; e += 256) {
        float l = al[csrc[e]] + arv;
        l = l > 0.f ? l : NEG_SLOPE * l;
        m = fmaxf(m, l);
    }
#pragma unroll
    for (int off = 32; off; off >>= 1) m = fmaxf(m, __shfl_xor(m, off, 64));
    __shared__ float red[4];
    int wave = tid >> 6, lane = tid & 63;
    if (lane == 0) red[wave] = m;
    __syncthreads();
    m = fmaxf(fmaxf(red[0], red[1]), fmaxf(red[2], red[3]));
    __syncthreads();

    float acc[6] = {0.f, 0.f, 0.f, 0.f, 0.f, 0.f};
    float ssum = 0.f;
    __shared__ float sw[256];
    __shared__ int ssrc[256];
    for (int base = s0; base < s1; base += 256) {
        int e = base + tid;
        float w = 0.f; int si = 0;
        if (e < s1) {
            si = csrc[e];
            float l = al[si] + arv;
            l = l > 0.f ? l : NEG_SLOPE * l;
            w = __expf(l - m);
        }
        ssum += w;
        sw[tid] = w; ssrc[tid] = si;
        __syncthreads();
        int cnt = min(256, s1 - base);
        for (int j = 0; j < cnt; ++j) {
            float wj = sw[j];
            const bf16_t* hr = h2pre + (size_t)ssrc[j] * KP;
#pragma unroll
            for (int qq = 0; qq < 6; ++qq) {
                int f = tid + qq * 256;
                if (f < FOUT) acc[qq] += wj * b2f(hr[f]);
            }
        }
        __syncthreads();
    }
#pragma unroll
    for (int off = 32; off; off >>= 1) ssum += __shfl_xor(ssum, off, 64);
    if (lane == 0) red[wave] = ssum;
    __syncthreads();
    float inv = 1.f / (red[0] + red[1] + red[2] + red[3]);
#pragma unroll
    for (int qq = 0; qq < 6; ++qq) {
        int f = tid + qq * 256;
        if (f < KP) {
            float o = 0.f;
            if (f < FOUT) o = fmaxf(acc[qq] * inv + b2f(b2[f]), 0.f);
            h2[(size_t)v * KP + f] = f2b(o);
        }
    }
}

// ---------------- final: out = sigmoid(H @ H^T), bf16 MFMA 128x128 tiles, f32 store ----------------
__global__ __launch_bounds__(256) void k_gemm_sig(const bf16_t* __restrict__ Hm,
                                                  float* __restrict__ out) {
    __shared__ __align__(16) bf16_t As[128 * 32];
    __shared__ __align__(16) bf16_t Bs[128 * 32];
    const int tid = threadIdx.x;
    const int wave = tid >> 6;
    const int lane = tid & 63;
    const int rowA0 = blockIdx.y * 128;
    const int rowB0 = blockIdx.x * 128;

    // staging: lane i covers LDS row (c*64 + wave*16 + i/4), k-slot (i&3); data slot XOR-swizzled
    const int sRow  = wave * 16 + (lane >> 2);
    const int sSlot = (lane & 3) ^ ((lane >> 2) & 3);
    const bf16_t* gA = Hm + (size_t)(rowA0 + sRow) * KP + sSlot * 8;
    const bf16_t* gB = Hm + (size_t)(rowB0 + sRow) * KP + sSlot * 8;

    f32x4 acc[4][4] = {};

    const int wrow = wave >> 1, wcol = wave & 1;
    const int r = lane & 15, q = lane >> 4;
    const int rslot = q ^ (r & 3);            // data for k-slot q lives at LDS slot q^(row&3), row&3 == r&3
    const __bf16* Asb = (const __bf16*)As;
    const __bf16* Bsb = (const __bf16*)Bs;

    for (int kt = 0; kt < KP / 32; ++kt) {
        const int k0 = kt * 32;
#pragma unroll
        for (int c = 0; c < 2; ++c) {
            __builtin_amdgcn_global_load_lds(
                (const __attribute__((address_space(1))) void*)(gA + (size_t)c * 64 * KP + k0),
                (__attribute__((address_space(3))) void*)((char*)As + c * 4096 + wave * 1024),
                16, 0, 0);
            __builtin_amdgcn_global_load_lds(
                (const __attribute__((address_space(1))) void*)(gB + (size_t)c * 64 * KP + k0),
                (__attribute__((address_space(3))) void*)((char*)Bs + c * 4096 + wave * 1024),
                16, 0, 0);
        }
        __syncthreads();
        bf16x8 af[4], bfr[4];
#pragma unroll
        for (int mi = 0; mi < 4; ++mi)
            af[mi] = *(const bf16x8*)(Asb + ((wrow * 64 + mi * 16 + r) * 32 + rslot * 8));
#pragma unroll
        for (int ni = 0; ni < 4; ++ni)
            bfr[ni] = *(const bf16x8*)(Bsb + ((wcol * 64 + ni * 16 + r) * 32 + rslot * 8));
#pragma unroll
        for (int mi = 0; mi < 4; ++mi)
#pragma unroll
            for (int ni = 0; ni < 4; ++ni)
                acc[mi][ni] = __builtin_amdgcn_mfma_f32_16x16x32_bf16(af[mi], bfr[ni], acc[mi][ni], 0, 0, 0);
        __syncthreads();
    }

    // epilogue: sigmoid + f32 store. C/D layout: col=lane&15, row=(lane>>4)*4+reg
#pragma unroll
    for (int mi = 0; mi < 4; ++mi) {
        const int row0 = rowA0 + wrow * 64 + mi * 16 + q * 4;
#pragma unroll
        for (int ni = 0; ni < 4; ++ni) {
            const int col = rowB0 + wcol * 64 + ni * 16 + r;
            if (col < NNODES) {
#pragma unroll
                for (int r2 = 0; r2 < 4; ++r2) {
                    const int row = row0 + r2;
                    if (row < NNODES) {
                        float z = acc[mi][ni][r2];
                        out[(size_t)row * NNODES + col] = 1.f / (1.f + __expf(-z));
                    }
                }
            }
        }
    }
}

// ---------------- edge_index passthrough as f32 ----------------
__global__ void k_edges(const int* __restrict__ ei, float* __restrict__ outbase) {
    int i = blockIdx.x * blockDim.x + threadIdx.x;
    if (i < 2 * NEDGES)
        outbase[(size_t)NNODES * (size_t)NNODES + (size_t)i] = (float)ei[i];
}

extern "C" void kernel_launch(void* const* d_in, const int* in_sizes, int n_in,
                              void* d_out, int out_size, void* d_ws, size_t ws_size,
                              hipStream_t stream) {
    const bf16_t* x   = (const bf16_t*)d_in[0];
    const int*    ei  = (const int*)d_in[1];
    const bf16_t* W1  = (const bf16_t*)d_in[2];
    const bf16_t* as1 = (const bf16_t*)d_in[3];
    const bf16_t* ad1 = (const bf16_t*)d_in[4];
    const bf16_t* b1  = (const bf16_t*)d_in[5];
    const bf16_t* W2  = (const bf16_t*)d_in[6];
    const bf16_t* as2 = (const bf16_t*)d_in[7];
    const bf16_t* ad2 = (const bf16_t*)d_in[8];
    const bf16_t* b2  = (const bf16_t*)d_in[9];
    float* out = (float*)d_out;   // OUTPUT IS FLOAT32 (proven by round-1/2 forensics)

    // Scratch lives inside d_out's adjacency region (576 MB f32), dead until
    // k_gemm_sig overwrites it at the end. Only h2 (read during the final
    // GEMM) lives in d_ws: 34.65 MB workspace use.
    char* obuf = (char*)d_out;
    size_t off = 0;
    auto carve = [&](size_t bytes) {
        char* p = obuf + off;
        off += (bytes + 255) & ~(size_t)255;
        return p;
    };
    float* h1pre  = (float*)carve((size_t)NNODES * FHID * 4);
    float* al1    = (float*)carve((size_t)NNODES * 4);
    float* ar1    = (float*)carve((size_t)NNODES * 4);
    float* h1     = (float*)carve((size_t)NNODES * FHID * 4);
    float* al2    = (float*)carve((size_t)NNODES * 4);
    float* ar2    = (float*)carve((size_t)NNODES * 4);
    int*   deg    = (int*)carve((size_t)NNODES * 4);
    int*   rowptr = (int*)carve((size_t)(NNODES + 1) * 4);
    int*   cursor = (int*)carve((size_t)NNODES * 4);
    int*   csrc   = (int*)carve((size_t)NETOT * 4);
    bf16_t* h2pre = (bf16_t*)carve((size_t)NNODES * KP * 2);
    // total ~41.3 MB << 576 MB adjacency region
    bf16_t* h2 = (bf16_t*)d_ws;   // [MP][KP] bf16 = 34,652,160 bytes
    (void)ws_size; (void)in_sizes; (void)n_in; (void)out_size;

    hipLaunchKernelGGL(k_init,    dim3(256), dim3(256), 0, stream, deg, h2);
    hipLaunchKernelGGL(k_count,   dim3((NEDGES + 255) / 256), dim3(256), 0, stream, ei, deg);
    hipLaunchKernelGGL(k_scan,    dim3(1), dim3(1024), 0, stream, deg, rowptr);
    hipLaunchKernelGGL(k_cursor,  dim3((NNODES + 255) / 256), dim3(256), 0, stream, rowptr, cursor);
    hipLaunchKernelGGL(k_fill,    dim3((NETOT + 255) / 256), dim3(256), 0, stream, ei, cursor, csrc);
    hipLaunchKernelGGL(k_linear1, dim3((NNODES + 255) / 256), dim3(256), 0, stream,
                       x, W1, as1, ad1, h1pre, al1, ar1);
    hipLaunchKernelGGL(k_agg1,    dim3(NNODES), dim3(64), 0, stream,
                       h1pre, al1, ar1, rowptr, csrc, b1, h1);
    hipLaunchKernelGGL(k_linear2, dim3(NNODES), dim3(256), 0, stream,
                       h1, W2, as2, ad2, h2pre, al2, ar2);
    hipLaunchKernelGGL(k_agg2,    dim3(NNODES), dim3(256), 0, stream,
                       h2pre, al2, ar2, rowptr, csrc, b2, h2);
    hipLaunchKernelGGL(k_gemm_sig, dim3(MP / 128, MP / 128), dim3(256), 0, stream, h2, out);
    hipLaunchKernelGGL(k_edges,   dim3((2 * NEDGES + 255) / 256), dim3(256), 0, stream, ei, out);
}

// Round 4
// 1170.235 us; speedup vs baseline: 1.4200x; 1.4200x over previous
//
#include <hip/hip_runtime.h>
#include <hip/hip_bf16.h>

#define NNODES 12000
#define NEDGES 384000
#define NETOT  (NEDGES + NNODES)   /* 396000 incl self-loops */
#define FIN    4
#define FHID   50
#define FOUT   1433
#define KP     1440                /* FOUT padded to multiple of 32 */
#define MP     12032               /* NNODES padded to multiple of 128 */
#define NEG_SLOPE 0.2f

typedef __hip_bfloat16 bf16_t;
typedef __bf16 bf16x8 __attribute__((ext_vector_type(8)));
typedef float  f32x4  __attribute__((ext_vector_type(4)));

__device__ __forceinline__ float  b2f(bf16_t h) { return __bfloat162float(h); }
__device__ __forceinline__ bf16_t f2b(float f)  { return __float2bfloat16(f); }
__device__ __forceinline__ float  blo(unsigned v) { union { unsigned u; float f; } c; c.u = v << 16; return c.f; }
__device__ __forceinline__ float  bhi(unsigned v) { union { unsigned u; float f; } c; c.u = v & 0xFFFF0000u; return c.f; }
__device__ __forceinline__ unsigned short f2bu(float f) { bf16_t h = f2b(f); return *(unsigned short*)&h; }

// ---------------- init: deg=1 (self loop), zero pad rows of h2 ----------------
__global__ void k_init(int* __restrict__ deg, bf16_t* __restrict__ h2) {
    int i = blockIdx.x * blockDim.x + threadIdx.x;
    int stride = gridDim.x * blockDim.x;
    for (int v = i; v < NNODES; v += stride) deg[v] = 1;
    const size_t padN = (size_t)(MP - NNODES) * KP;
    for (size_t t = i; t < padN; t += stride) h2[(size_t)NNODES * KP + t] = f2b(0.f);
}

// ---------------- count real edges by dst ----------------
__global__ void k_count(const int* __restrict__ ei, int* __restrict__ deg) {
    int i = blockIdx.x * blockDim.x + threadIdx.x;
    if (i < NEDGES) atomicAdd(&deg[ei[NEDGES + i]], 1);
}

// ---------------- single-block exclusive scan -> rowptr[N+1] ----------------
__global__ __launch_bounds__(1024) void k_scan(const int* __restrict__ deg, int* __restrict__ rowptr) {
    __shared__ int sd[1024];
    __shared__ int carry;
    int tid = threadIdx.x;
    if (tid == 0) { carry = 0; rowptr[0] = 0; }
    __syncthreads();
    for (int base = 0; base < NNODES; base += 1024) {
        int v = (base + tid < NNODES) ? deg[base + tid] : 0;
        sd[tid] = v;
        __syncthreads();
        for (int off = 1; off < 1024; off <<= 1) {
            int t = (tid >= off) ? sd[tid - off] : 0;
            __syncthreads();
            sd[tid] += t;
            __syncthreads();
        }
        int inc = sd[tid] + carry;
        if (base + tid < NNODES) rowptr[base + tid + 1] = inc;
        __syncthreads();
        if (tid == 1023) carry = sd[1023] + carry;
        __syncthreads();
    }
}

__global__ void k_cursor(const int* __restrict__ rowptr, int* __restrict__ cursor) {
    int i = blockIdx.x * blockDim.x + threadIdx.x;
    if (i < NNODES) cursor[i] = rowptr[i];
}

// ---------------- fill CSR src lists (incl self loops) ----------------
__global__ void k_fill(const int* __restrict__ ei, int* __restrict__ cursor, int* __restrict__ csrc) {
    int i = blockIdx.x * blockDim.x + threadIdx.x;
    if (i < NETOT) {
        int s, d;
        if (i < NEDGES) { s = ei[i]; d = ei[NEDGES + i]; }
        else            { s = d = i - NEDGES; }
        int pos = atomicAdd(&cursor[d], 1);
        csrc[pos] = s;
    }
}

// ---------------- layer1 linear: h1pre = x @ W1, al1/ar1 logit parts ----------------
__global__ __launch_bounds__(256) void k_linear1(
        const bf16_t* __restrict__ x, const bf16_t* __restrict__ W1,
        const bf16_t* __restrict__ as1, const bf16_t* __restrict__ ad1,
        float* __restrict__ h1pre, float* __restrict__ al, float* __restrict__ ar) {
    __shared__ float sW[FIN * FHID];
    __shared__ float sa[FHID], sdl[FHID];
    int tid = threadIdx.x;
    if (tid < FIN * FHID) sW[tid] = b2f(W1[tid]);
    if (tid < FHID) { sa[tid] = b2f(as1[tid]); sdl[tid] = b2f(ad1[tid]); }
    __syncthreads();
    int i = blockIdx.x * 256 + tid;
    if (i >= NNODES) return;
    float x0 = b2f(x[i * 4 + 0]), x1 = b2f(x[i * 4 + 1]);
    float x2 = b2f(x[i * 4 + 2]), x3 = b2f(x[i * 4 + 3]);
    float hal = 0.f, har = 0.f;
    for (int j = 0; j < FHID; ++j) {
        float h = x0 * sW[j] + x1 * sW[FHID + j] + x2 * sW[2 * FHID + j] + x3 * sW[3 * FHID + j];
        h1pre[(size_t)i * FHID + j] = h;
        hal += h * sa[j];
        har += h * sdl[j];
    }
    al[i] = hal; ar[i] = har;
}

// ---------------- layer1 softmax-aggregate (one wave per dst) ----------------
__global__ __launch_bounds__(64) void k_agg1(
        const float* __restrict__ h1pre, const float* __restrict__ al, const float* __restrict__ ar,
        const int* __restrict__ rowptr, const int* __restrict__ csrc,
        const bf16_t* __restrict__ b1, float* __restrict__ h1) {
    int v = blockIdx.x, tid = threadIdx.x;
    int s0 = rowptr[v], s1 = rowptr[v + 1];
    float arv = ar[v];
    float m = -1e30f;
    for (int e = s0 + tid; e < s1; e += 64) {
        float l = al[csrc[e]] + arv;
        l = l > 0.f ? l : NEG_SLOPE * l;
        m = fmaxf(m, l);
    }
#pragma unroll
    for (int off = 32; off; off >>= 1) m = fmaxf(m, __shfl_xor(m, off, 64));
    __shared__ float sw[64];
    __shared__ int ssrc[64];
    float acc = 0.f, ssum = 0.f;
    for (int base = s0; base < s1; base += 64) {
        int e = base + tid;
        float w = 0.f; int si = 0;
        if (e < s1) {
            si = csrc[e];
            float l = al[si] + arv;
            l = l > 0.f ? l : NEG_SLOPE * l;
            w = __expf(l - m);
        }
        ssum += w;
        sw[tid] = w; ssrc[tid] = si;
        __syncthreads();
        int cnt = min(64, s1 - base);
        if (tid < FHID) {
            for (int j = 0; j < cnt; ++j)
                acc += sw[j] * h1pre[(size_t)ssrc[j] * FHID + tid];
        }
        __syncthreads();
    }
#pragma unroll
    for (int off = 32; off; off >>= 1) ssum += __shfl_xor(ssum, off, 64);
    if (tid < FHID) {
        float o = acc / ssum + b2f(b1[tid]);
        h1[(size_t)v * FHID + tid] = fmaxf(o, 0.f);
    }
}

// ---------------- layer2 linear: 4 nodes/block, h2pre = h1 @ W2 (bf16, stride KP), al2/ar2 ----------------
__global__ __launch_bounds__(256) void k_linear2(
        const float* __restrict__ h1, const bf16_t* __restrict__ W2,
        const bf16_t* __restrict__ as2, const bf16_t* __restrict__ ad2,
        bf16_t* __restrict__ h2pre, float* __restrict__ al2, float* __restrict__ ar2) {
    int v0 = blockIdx.x * 4, tid = threadIdx.x;
    __shared__ float sh[4][FHID];
    if (tid < 4 * FHID) sh[tid / FHID][tid % FHID] = h1[(size_t)v0 * FHID + tid];
    __syncthreads();
    float pal[4] = {0.f, 0.f, 0.f, 0.f}, par[4] = {0.f, 0.f, 0.f, 0.f};
    for (int f = tid; f < KP; f += 256) {
        float a[4] = {0.f, 0.f, 0.f, 0.f};
        if (f < FOUT) {
#pragma unroll 10
            for (int k = 0; k < FHID; ++k) {
                float w = b2f(W2[k * FOUT + f]);
                a[0] += sh[0][k] * w; a[1] += sh[1][k] * w;
                a[2] += sh[2][k] * w; a[3] += sh[3][k] * w;
            }
            float sa = b2f(as2[f]), sd = b2f(ad2[f]);
#pragma unroll
            for (int c = 0; c < 4; ++c) { pal[c] += a[c] * sa; par[c] += a[c] * sd; }
        }
#pragma unroll
        for (int c = 0; c < 4; ++c) h2pre[(size_t)(v0 + c) * KP + f] = f2b(a[c]);
    }
#pragma unroll
    for (int off = 32; off; off >>= 1)
#pragma unroll
        for (int c = 0; c < 4; ++c) {
            pal[c] += __shfl_xor(pal[c], off, 64);
            par[c] += __shfl_xor(par[c], off, 64);
        }
    __shared__ float rA[4][4], rB[4][4];
    int wave = tid >> 6, lane = tid & 63;
    if (lane == 0)
#pragma unroll
        for (int c = 0; c < 4; ++c) { rA[wave][c] = pal[c]; rB[wave][c] = par[c]; }
    __syncthreads();
    if (tid < 4) {
        al2[v0 + tid] = rA[0][tid] + rA[1][tid] + rA[2][tid] + rA[3][tid];
        ar2[v0 + tid] = rB[0][tid] + rB[1][tid] + rB[2][tid] + rB[3][tid];
    }
}

// ---------------- layer2 softmax-aggregate: uint2 gather (8B/lane), writes h2 bf16 [MP][KP] ----------------
__global__ __launch_bounds__(256) void k_agg2(
        const bf16_t* __restrict__ h2pre, const float* __restrict__ al, const float* __restrict__ ar,
        const int* __restrict__ rowptr, const int* __restrict__ csrc,
        const bf16_t* __restrict__ bias2, bf16_t* __restrict__ h2) {
    int v = blockIdx.x, tid = threadIdx.x;
    int s0 = rowptr[v], s1 = rowptr[v + 1];
    float arv = ar[v];
    float m = -1e30f;
    for (int e = s0 + tid; e < s1; e += 256) {
        float l = al[csrc[e]] + arv;
        l = l > 0.f ? l : NEG_SLOPE * l;
        m = fmaxf(m, l);
    }
#pragma unroll
    for (int off = 32; off; off >>= 1) m = fmaxf(m, __shfl_xor(m, off, 64));
    __shared__ float red[4];
    int wave = tid >> 6, lane = tid & 63;
    if (lane == 0) red[wave] = m;
    __syncthreads();
    m = fmaxf(fmaxf(red[0], red[1]), fmaxf(red[2], red[3]));
    __syncthreads();

    // thread covers uint2 slots u=tid (features 4t..4t+3) and u=256+tid if tid<104 (features 1024+4t..)
    float a0 = 0.f, a1 = 0.f, a2 = 0.f, a3 = 0.f;
    float c0 = 0.f, c1 = 0.f, c2 = 0.f, c3 = 0.f;
    float ssum = 0.f;
    __shared__ float sw[256];
    __shared__ int ssrc[256];
    const bool hi = (tid < (360 - 256));
    for (int base = s0; base < s1; base += 256) {
        int e = base + tid;
        float w = 0.f; int si = 0;
        if (e < s1) {
            si = csrc[e];
            float l = al[si] + arv;
            l = l > 0.f ? l : NEG_SLOPE * l;
            w = __expf(l - m);
        }
        ssum += w;
        sw[tid] = w; ssrc[tid] = si;
        __syncthreads();
        int cnt = min(256, s1 - base);
#pragma unroll 4
        for (int j = 0; j < cnt; ++j) {
            float wj = sw[j];
            const uint2* hp = (const uint2*)(h2pre + (size_t)ssrc[j] * KP);
            uint2 p = hp[tid];
            a0 += wj * blo(p.x); a1 += wj * bhi(p.x);
            a2 += wj * blo(p.y); a3 += wj * bhi(p.y);
            if (hi) {
                uint2 q2 = hp[256 + tid];
                c0 += wj * blo(q2.x); c1 += wj * bhi(q2.x);
                c2 += wj * blo(q2.y); c3 += wj * bhi(q2.y);
            }
        }
        __syncthreads();
    }
#pragma unroll
    for (int off = 32; off; off >>= 1) ssum += __shfl_xor(ssum, off, 64);
    if (lane == 0) red[wave] = ssum;
    __syncthreads();
    float inv = 1.f / (red[0] + red[1] + red[2] + red[3]);

    // writeback: 8B vectorized (4 bf16 per store)
    {
        int fb = 4 * tid;   // 0..1020, all < FOUT
        ushort4 pk;
        pk.x = f2bu(fmaxf(a0 * inv + b2f(bias2[fb + 0]), 0.f));
        pk.y = f2bu(fmaxf(a1 * inv + b2f(bias2[fb + 1]), 0.f));
        pk.z = f2bu(fmaxf(a2 * inv + b2f(bias2[fb + 2]), 0.f));
        pk.w = f2bu(fmaxf(a3 * inv + b2f(bias2[fb + 3]), 0.f));
        *(ushort4*)(h2 + (size_t)v * KP + fb) = pk;
    }
    if (hi) {
        int fb = 1024 + 4 * tid;   // 1024..1436; features >= FOUT zeroed
        float vv[4] = {c0, c1, c2, c3};
        ushort4 pk;
        unsigned short* pp = (unsigned short*)&pk;
#pragma unroll
        for (int t = 0; t < 4; ++t) {
            int f = fb + t;
            float o = (f < FOUT) ? fmaxf(vv[t] * inv + b2f(bias2[f]), 0.f) : 0.f;
            pp[t] = f2bu(o);
        }
        *(ushort4*)(h2 + (size_t)v * KP + fb) = pk;
    }
}

// ---------------- final: out = sigmoid(H @ H^T), symmetric — upper-triangle blocks only ----------------
__global__ __launch_bounds__(256) void k_gemm_sig(const bf16_t* __restrict__ Hm,
                                                  float* __restrict__ out) {
    const int bx = blockIdx.x, by = blockIdx.y;
    if (bx < by) return;   // C is symmetric: compute by<=bx, write both tiles
    __shared__ __align__(16) bf16_t As[128 * 32];
    __shared__ __align__(16) bf16_t Bs[128 * 32];
    const int tid = threadIdx.x;
    const int wave = tid >> 6;
    const int lane = tid & 63;
    const int rowA0 = by * 128;
    const int rowB0 = bx * 128;

    const int sRow  = wave * 16 + (lane >> 2);
    const int sSlot = (lane & 3) ^ ((lane >> 2) & 3);
    const bf16_t* gA = Hm + (size_t)(rowA0 + sRow) * KP + sSlot * 8;
    const bf16_t* gB = Hm + (size_t)(rowB0 + sRow) * KP + sSlot * 8;

    f32x4 acc[4][4] = {};

    const int wrow = wave >> 1, wcol = wave & 1;
    const int r = lane & 15, q = lane >> 4;
    const int rslot = q ^ (r & 3);
    const __bf16* Asb = (const __bf16*)As;
    const __bf16* Bsb = (const __bf16*)Bs;

    for (int kt = 0; kt < KP / 32; ++kt) {
        const int k0 = kt * 32;
#pragma unroll
        for (int c = 0; c < 2; ++c) {
            __builtin_amdgcn_global_load_lds(
                (const __attribute__((address_space(1))) void*)(gA + (size_t)c * 64 * KP + k0),
                (__attribute__((address_space(3))) void*)((char*)As + c * 4096 + wave * 1024),
                16, 0, 0);
            __builtin_amdgcn_global_load_lds(
                (const __attribute__((address_space(1))) void*)(gB + (size_t)c * 64 * KP + k0),
                (__attribute__((address_space(3))) void*)((char*)Bs + c * 4096 + wave * 1024),
                16, 0, 0);
        }
        __syncthreads();
        bf16x8 af[4], bfr[4];
#pragma unroll
        for (int mi = 0; mi < 4; ++mi)
            af[mi] = *(const bf16x8*)(Asb + ((wrow * 64 + mi * 16 + r) * 32 + rslot * 8));
#pragma unroll
        for (int ni = 0; ni < 4; ++ni)
            bfr[ni] = *(const bf16x8*)(Bsb + ((wcol * 64 + ni * 16 + r) * 32 + rslot * 8));
#pragma unroll
        for (int mi = 0; mi < 4; ++mi)
#pragma unroll
            for (int ni = 0; ni < 4; ++ni)
                acc[mi][ni] = __builtin_amdgcn_mfma_f32_16x16x32_bf16(af[mi], bfr[ni], acc[mi][ni], 0, 0, 0);
        __syncthreads();
    }

    // epilogue. C/D layout: col=lane&15, row=(lane>>4)*4+reg. N%4==0 and row0%4==0
    // => the 4-row quad is all-valid iff row0 < N.
#pragma unroll
    for (int mi = 0; mi < 4; ++mi) {
        const int row0 = rowA0 + wrow * 64 + mi * 16 + q * 4;
#pragma unroll
        for (int ni = 0; ni < 4; ++ni) {
            const int col = rowB0 + wcol * 64 + ni * 16 + r;
            if (col < NNODES && row0 < NNODES) {
                f32x4 s;
#pragma unroll
                for (int r2 = 0; r2 < 4; ++r2)
                    s[r2] = 1.f / (1.f + __expf(-acc[mi][ni][r2]));
#pragma unroll
                for (int r2 = 0; r2 < 4; ++r2)
                    out[(size_t)(row0 + r2) * NNODES + col] = s[r2];
                if (bx != by)   // mirrored tile: contiguous float4 store
                    *(f32x4*)(out + (size_t)col * NNODES + row0) = s;
            }
        }
    }
}

// ---------------- edge_index passthrough as f32 ----------------
__global__ void k_edges(const int* __restrict__ ei, float* __restrict__ outbase) {
    int i = blockIdx.x * blockDim.x + threadIdx.x;
    if (i < 2 * NEDGES)
        outbase[(size_t)NNODES * (size_t)NNODES + (size_t)i] = (float)ei[i];
}

extern "C" void kernel_launch(void* const* d_in, const int* in_sizes, int n_in,
                              void* d_out, int out_size, void* d_ws, size_t ws_size,
                              hipStream_t stream) {
    const bf16_t* x   = (const bf16_t*)d_in[0];
    const int*    ei  = (const int*)d_in[1];
    const bf16_t* W1  = (const bf16_t*)d_in[2];
    const bf16_t* as1 = (const bf16_t*)d_in[3];
    const bf16_t* ad1 = (const bf16_t*)d_in[4];
    const bf16_t* b1  = (const bf16_t*)d_in[5];
    const bf16_t* W2  = (const bf16_t*)d_in[6];
    const bf16_t* as2 = (const bf16_t*)d_in[7];
    const bf16_t* ad2 = (const bf16_t*)d_in[8];
    const bf16_t* b2  = (const bf16_t*)d_in[9];
    float* out = (float*)d_out;   // output 0 is f32 [N][N], output 1 f32 [2][E]

    // Scratch lives inside d_out's adjacency region (576 MB f32), dead until
    // k_gemm_sig overwrites it at the end. Only h2 (read during the final
    // GEMM) lives in d_ws: 34.65 MB workspace use.
    char* obuf = (char*)d_out;
    size_t off = 0;
    auto carve = [&](size_t bytes) {
        char* p = obuf + off;
        off += (bytes + 255) & ~(size_t)255;
        return p;
    };
    float* h1pre  = (float*)carve((size_t)NNODES * FHID * 4);
    float* al1    = (float*)carve((size_t)NNODES * 4);
    float* ar1    = (float*)carve((size_t)NNODES * 4);
    float* h1     = (float*)carve((size_t)NNODES * FHID * 4);
    float* al2    = (float*)carve((size_t)NNODES * 4);
    float* ar2    = (float*)carve((size_t)NNODES * 4);
    int*   deg    = (int*)carve((size_t)NNODES * 4);
    int*   rowptr = (int*)carve((size_t)(NNODES + 1) * 4);
    int*   cursor = (int*)carve((size_t)NNODES * 4);
    int*   csrc   = (int*)carve((size_t)NETOT * 4);
    bf16_t* h2pre = (bf16_t*)carve((size_t)NNODES * KP * 2);
    bf16_t* h2 = (bf16_t*)d_ws;   // [MP][KP] bf16 = 34,652,160 bytes
    (void)ws_size; (void)in_sizes; (void)n_in; (void)out_size;

    hipLaunchKernelGGL(k_init,    dim3(256), dim3(256), 0, stream, deg, h2);
    hipLaunchKernelGGL(k_count,   dim3((NEDGES + 255) / 256), dim3(256), 0, stream, ei, deg);
    hipLaunchKernelGGL(k_scan,    dim3(1), dim3(1024), 0, stream, deg, rowptr);
    hipLaunchKernelGGL(k_cursor,  dim3((NNODES + 255) / 256), dim3(256), 0, stream, rowptr, cursor);
    hipLaunchKernelGGL(k_fill,    dim3((NETOT + 255) / 256), dim3(256), 0, stream, ei, cursor, csrc);
    hipLaunchKernelGGL(k_linear1, dim3((NNODES + 255) / 256), dim3(256), 0, stream,
                       x, W1, as1, ad1, h1pre, al1, ar1);
    hipLaunchKernelGGL(k_agg1,    dim3(NNODES), dim3(64), 0, stream,
                       h1pre, al1, ar1, rowptr, csrc, b1, h1);
    hipLaunchKernelGGL(k_linear2, dim3(NNODES / 4), dim3(256), 0, stream,
                       h1, W2, as2, ad2, h2pre, al2, ar2);
    hipLaunchKernelGGL(k_agg2,    dim3(NNODES), dim3(256), 0, stream,
                       h2pre, al2, ar2, rowptr, csrc, b2, h2);
    hipLaunchKernelGGL(k_gemm_sig, dim3(MP / 128, MP / 128), dim3(256), 0, stream, h2, out);
    hipLaunchKernelGGL(k_edges,   dim3((2 * NEDGES + 255) / 256), dim3(256), 0, stream, ei, out);
}